// Round 7
// baseline (238.632 us; speedup 1.0000x reference)
//
#include <hip/hip_runtime.h>
#include <hip/hip_bf16.h>
#include <stdint.h>

// B=2, S=4096, D=512, H=8, dk=64. fp32 in/out, bf16 MFMA internals.
// R7: attn restructured — K/V MFMA fragments are 16B-contiguous in the
// Kg[s][64] / Vtg[d][4096] layouts, so load them global->VGPR directly
// (L2-resident, ~2MB/head). No K/V LDS staging, no double buffer, NO
// barriers (1-wave blocks, 64 q/wave). Register-level software pipeline:
// next tile's 16 b128 loads issue before current tile's MFMAs. LDS holds
// only the 8KB P-transpose strips (S^T b64-write / A-layout b128-read).

typedef __bf16 bf16;
typedef __attribute__((ext_vector_type(8))) __bf16 bf16x8;
typedef __attribute__((ext_vector_type(4))) __bf16 bf16x4;
typedef __attribute__((ext_vector_type(4))) float f32x4;

#define LOG2E 1.44269504088896340736f
// Swizzled elem offset of an 8-elem group in a [rows][64] bf16 LDS tile.
#define SW(row, grp) (((row) << 6) + ((((grp) ^ ((row) & 7))) << 3))

// ---------------------------------------------------------------- LayerNorm
__global__ __launch_bounds__(256) void ln_kernel(
    const float* __restrict__ x, const float* __restrict__ gamma,
    const float* __restrict__ beta, bf16* __restrict__ h) {
  int wave = threadIdx.x >> 6, lane = threadIdx.x & 63;
  int row = blockIdx.x * 4 + wave;                 // 8192 rows
  const float* xr = x + (size_t)row * 512 + lane * 8;
  f32x4 v0 = *(const f32x4*)xr;
  f32x4 v1 = *(const f32x4*)(xr + 4);
  float f[8], s = 0.f, s2 = 0.f;
#pragma unroll
  for (int i = 0; i < 4; ++i) { f[i] = v0[i]; f[4 + i] = v1[i]; }
#pragma unroll
  for (int i = 0; i < 8; ++i) { s += f[i]; s2 += f[i] * f[i]; }
#pragma unroll
  for (int off = 1; off < 64; off <<= 1) {
    s  += __shfl_xor(s, off, 64);
    s2 += __shfl_xor(s2, off, 64);
  }
  float mu  = s * (1.f / 512.f);
  float var = s2 * (1.f / 512.f) - mu * mu;
  float rstd = rsqrtf(var + 1e-5f);
  f32x4 g0 = *(const f32x4*)(gamma + lane * 8);
  f32x4 g1 = *(const f32x4*)(gamma + lane * 8 + 4);
  f32x4 b0 = *(const f32x4*)(beta + lane * 8);
  f32x4 b1 = *(const f32x4*)(beta + lane * 8 + 4);
  bf16x8 o;
#pragma unroll
  for (int i = 0; i < 4; ++i) {
    o[i]     = (bf16)((f[i]     - mu) * rstd * g0[i] + b0[i]);
    o[4 + i] = (bf16)((f[4 + i] - mu) * rstd * g1[i] + b1[i]);
  }
  *(bf16x8*)(h + (size_t)row * 512 + lane * 8) = o;
}

// ------------------------------------------------------------- QKV GEMM
__global__ __launch_bounds__(256) void qkv_kernel(
    const bf16* __restrict__ h, const float* __restrict__ wq,
    const float* __restrict__ wk, const float* __restrict__ wv,
    bf16* __restrict__ Qg, bf16* __restrict__ Kg, bf16* __restrict__ Vtg) {
  __shared__ bf16 As[128 * 64];
  __shared__ bf16 Bs[128 * 64];
  int tid = threadIdx.x, wave = tid >> 6, lane = tid & 63;
  int wm = wave >> 1, wn = wave & 1, quad = lane >> 4, l15 = lane & 15;
  int mtile = blockIdx.x;          // 0..63
  int wsel = blockIdx.y >> 2;      // 0=q 1=k 2=v
  int nb = blockIdx.y & 3;
  const float* W = (wsel == 0) ? wq : (wsel == 1 ? wk : wv);
  const bf16*  Abase = h + (size_t)mtile * 128 * 512;
  const float* Bbase = W + (size_t)nb * 128 * 512;
  f32x4 acc[4][4];
#pragma unroll
  for (int i = 0; i < 4; ++i)
#pragma unroll
    for (int j = 0; j < 4; ++j) acc[i][j] = (f32x4){0.f, 0.f, 0.f, 0.f};

  int srow = tid >> 3, grp = tid & 7, scol = grp * 8;
  bf16x8 ar[4];
  f32x4 br0[4], br1[4];
#pragma unroll
  for (int k = 0; k < 4; ++k) {                 // prologue: tile 0 loads
    int rr = srow + k * 32;
    ar[k]  = *(const bf16x8*)(Abase + (size_t)rr * 512 + scol);
    br0[k] = *(const f32x4*)(Bbase + (size_t)rr * 512 + scol);
    br1[k] = *(const f32x4*)(Bbase + (size_t)rr * 512 + scol + 4);
  }
  for (int k0 = 0; k0 < 512; k0 += 64) {
#pragma unroll
    for (int k = 0; k < 4; ++k) {               // regs -> LDS
      int rr = srow + k * 32;
      int w = SW(rr, grp);
      *(bf16x8*)(As + w) = ar[k];
      bf16x8 wb;
#pragma unroll
      for (int j = 0; j < 4; ++j) { wb[j] = (bf16)br0[k][j]; wb[4 + j] = (bf16)br1[k][j]; }
      *(bf16x8*)(Bs + w) = wb;
    }
    __syncthreads();
    if (k0 < 448) {                             // prefetch next tile
#pragma unroll
      for (int k = 0; k < 4; ++k) {
        int rr = srow + k * 32;
        ar[k]  = *(const bf16x8*)(Abase + (size_t)rr * 512 + k0 + 64 + scol);
        br0[k] = *(const f32x4*)(Bbase + (size_t)rr * 512 + k0 + 64 + scol);
        br1[k] = *(const f32x4*)(Bbase + (size_t)rr * 512 + k0 + 64 + scol + 4);
      }
    }
#pragma unroll
    for (int c = 0; c < 2; ++c) {
      bf16x8 af[4], bw[4];
#pragma unroll
      for (int mt = 0; mt < 4; ++mt)
        af[mt] = *(const bf16x8*)(As + SW(wm * 64 + mt * 16 + l15, c * 4 + quad));
#pragma unroll
      for (int nt = 0; nt < 4; ++nt)
        bw[nt] = *(const bf16x8*)(Bs + SW(wn * 64 + nt * 16 + l15, c * 4 + quad));
#pragma unroll
      for (int mt = 0; mt < 4; ++mt)
#pragma unroll
        for (int nt = 0; nt < 4; ++nt)
          acc[mt][nt] = __builtin_amdgcn_mfma_f32_16x16x32_bf16(
              bw[nt], af[mt], acc[mt][nt], 0, 0, 0);
    }
    __syncthreads();
  }
  // Q pre-scale folds softmax 1/sqrt(64) AND log2(e) for exp2-based softmax.
  float qscale = (wsel == 0) ? (0.125f * LOG2E) : 1.0f;
#pragma unroll
  for (int mt = 0; mt < 4; ++mt) {
    int m_g = mtile * 128 + wm * 64 + mt * 16 + l15;   // token
    int b = m_g >> 12, s = m_g & 4095;
#pragma unroll
    for (int nt = 0; nt < 4; ++nt) {
      int n_g = nb * 128 + wn * 64 + nt * 16 + quad * 4;  // feature
      int head = n_g >> 6, d = n_g & 63;
      f32x4 a = acc[mt][nt];
      if (wsel < 2) {
        bf16* dst = (wsel == 0 ? Qg : Kg) +
                    ((size_t)((b * 8 + head) * 4096 + s)) * 64 + d;
        bf16x4 pk;
#pragma unroll
        for (int r = 0; r < 4; ++r) pk[r] = (bf16)(a[r] * qscale);
        *(bf16x4*)dst = pk;
      } else {
        bf16* dst = Vtg + ((size_t)((b * 8 + head) * 64 + d)) * 4096 + s;
#pragma unroll
        for (int r = 0; r < 4; ++r) dst[(size_t)r * 4096] = (bf16)a[r];
      }
    }
  }
}

// --------------------------------------------------------- Flash attention
// One wave per block, 64 q-rows. K/V fragments straight from global (L2).
__device__ __forceinline__ void attn_tile(
    const bf16* __restrict__ Kh, const bf16* __restrict__ Vth,
    int kt, int ktn, bool pf,
    bf16x8 (&kfc)[8], bf16x8 (&vfc)[8],
    bf16x8 (&kfn)[8], bf16x8 (&vfn)[8],
    const bf16x8 (&qf)[4][2], f32x4 (&o_acc)[4][4], float (&l_part)[4],
    bf16* __restrict__ Ps, int quad, int l15) {
  // ---- prefetch next tile's K/V fragments (global, 16B/lane, L2-hot)
  if (pf) {
#pragma unroll
    for (int kb = 0; kb < 4; ++kb)
#pragma unroll
      for (int c = 0; c < 2; ++c)
        kfn[kb * 2 + c] = *(const bf16x8*)(
            Kh + (size_t)(ktn * 64 + kb * 16 + l15) * 64 + c * 32 + quad * 8);
#pragma unroll
    for (int nt = 0; nt < 4; ++nt)
#pragma unroll
      for (int c = 0; c < 2; ++c)
        vfn[nt * 2 + c] = *(const bf16x8*)(
            Vth + (size_t)(nt * 16 + l15) * 4096 + ktn * 64 + c * 32 + quad * 8);
  }
  // ---- QK^T transposed per mt: S^T[key=kb*16+quad*4+r][q=l15]
#pragma unroll
  for (int mt = 0; mt < 4; ++mt) {
    f32x4 st[4];
#pragma unroll
    for (int kb = 0; kb < 4; ++kb) st[kb] = (f32x4){0.f, 0.f, 0.f, 0.f};
#pragma unroll
    for (int c = 0; c < 2; ++c)
#pragma unroll
      for (int kb = 0; kb < 4; ++kb)
        st[kb] = __builtin_amdgcn_mfma_f32_16x16x32_bf16(
            kfc[kb * 2 + c], qf[mt][c], st[kb], 0, 0, 0);
#pragma unroll
    for (int kb = 0; kb < 4; ++kb) {
      bf16x4 pk;
#pragma unroll
      for (int r = 0; r < 4; ++r) {
        float pv = __builtin_amdgcn_exp2f(st[kb][r]);
        l_part[mt] += pv;
        pk[r] = (bf16)pv;
      }
      *(bf16x4*)(&Ps[mt * 1024 +
                     SW(l15, kb * 2 + (quad >> 1)) + (quad & 1) * 4]) = pk;
    }
  }
  asm volatile("s_waitcnt lgkmcnt(0)" ::: "memory");  // wave-local P fence
  // ---- PV: O[q][d=nt*16+l15]
#pragma unroll
  for (int c = 0; c < 2; ++c) {
    bf16x8 pfr[4];
#pragma unroll
    for (int mt = 0; mt < 4; ++mt)
      pfr[mt] = *(const bf16x8*)(&Ps[mt * 1024 + SW(l15, c * 4 + quad)]);
#pragma unroll
    for (int nt = 0; nt < 4; ++nt)
#pragma unroll
      for (int mt = 0; mt < 4; ++mt)
        o_acc[mt][nt] = __builtin_amdgcn_mfma_f32_16x16x32_bf16(
            pfr[mt], vfc[nt * 2 + c], o_acc[mt][nt], 0, 0, 0);
  }
}

__global__ __launch_bounds__(64, 1) void attn_kernel(
    const bf16* __restrict__ Qg, const bf16* __restrict__ Kg,
    const bf16* __restrict__ Vtg, bf16* __restrict__ Og) {
  __shared__ bf16 Ps[4 * 16 * 64];      // 8 KB: per-mt P strips [16q][64key]
  int lane = threadIdx.x;
  int quad = lane >> 4, l15 = lane & 15;
  int q0 = blockIdx.x * 64;
  int bh = blockIdx.y;
  int hi = bh & 7, bi = bh >> 3;
  const bf16* Kh  = Kg  + (size_t)bh * 4096 * 64;
  const bf16* Vth = Vtg + (size_t)bh * 64 * 4096;

  bf16x8 qf[4][2];   // Q pre-scaled by 0.125*LOG2E in qkv
#pragma unroll
  for (int mt = 0; mt < 4; ++mt)
#pragma unroll
    for (int c = 0; c < 2; ++c)
      qf[mt][c] = *(const bf16x8*)(
          Qg + ((size_t)bh * 4096 + q0 + mt * 16 + l15) * 64 + c * 32 + quad * 8);

  f32x4 o_acc[4][4];
  float l_part[4] = {0.f, 0.f, 0.f, 0.f};
#pragma unroll
  for (int mt = 0; mt < 4; ++mt)
#pragma unroll
    for (int nt = 0; nt < 4; ++nt) o_acc[mt][nt] = (f32x4){0.f, 0.f, 0.f, 0.f};

  bf16x8 kfA[8], vfA[8], kfB[8], vfB[8];
  // prologue: tile 0 fragments
#pragma unroll
  for (int kb = 0; kb < 4; ++kb)
#pragma unroll
    for (int c = 0; c < 2; ++c)
      kfA[kb * 2 + c] = *(const bf16x8*)(
          Kh + (size_t)(kb * 16 + l15) * 64 + c * 32 + quad * 8);
#pragma unroll
  for (int nt = 0; nt < 4; ++nt)
#pragma unroll
    for (int c = 0; c < 2; ++c)
      vfA[nt * 2 + c] = *(const bf16x8*)(
          Vth + (size_t)(nt * 16 + l15) * 4096 + c * 32 + quad * 8);

  for (int kt = 0; kt < 64; kt += 2) {
    attn_tile(Kh, Vth, kt, kt + 1, true,
              kfA, vfA, kfB, vfB, qf, o_acc, l_part, Ps, quad, l15);
    attn_tile(Kh, Vth, kt + 1, kt + 2, (kt + 2) < 64,
              kfB, vfB, kfA, vfA, qf, o_acc, l_part, Ps, quad, l15);
  }
  // ---- l: reduce across quads (lanes same l15), then row-indexed fetch
#pragma unroll
  for (int mt = 0; mt < 4; ++mt) {
    l_part[mt] += __shfl_xor(l_part[mt], 16, 64);
    l_part[mt] += __shfl_xor(l_part[mt], 32, 64);
  }
#pragma unroll
  for (int mt = 0; mt < 4; ++mt)
#pragma unroll
    for (int r = 0; r < 4; ++r) {
      float lr = __shfl(l_part[mt], quad * 4 + r, 64);  // lane l15==q holds l
      float inv = 1.0f / lr;
      int q = q0 + mt * 16 + quad * 4 + r;
      size_t row = ((size_t)bi * 4096 + q) * 512 + hi * 64;
#pragma unroll
      for (int nt = 0; nt < 4; ++nt)
        Og[row + nt * 16 + l15] = (bf16)(o_acc[mt][nt][r] * inv);
    }
}

// ----------------------------------------------- out = A @ Wo^T + bo + x
__global__ __launch_bounds__(256) void proj_kernel(
    const bf16* __restrict__ A, const float* __restrict__ Wo,
    const float* __restrict__ bo, const float* __restrict__ x,
    float* __restrict__ out) {
  __shared__ bf16 As[128 * 64];
  __shared__ bf16 Bs[128 * 64];
  int tid = threadIdx.x, wave = tid >> 6, lane = tid & 63;
  int wm = wave >> 1, wn = wave & 1, quad = lane >> 4, l15 = lane & 15;
  int mtile = blockIdx.x, nb = blockIdx.y;
  const bf16*  Abase = A + (size_t)mtile * 128 * 512;
  const float* Bbase = Wo + (size_t)nb * 128 * 512;
  f32x4 acc[4][4];
#pragma unroll
  for (int i = 0; i < 4; ++i)
#pragma unroll
    for (int j = 0; j < 4; ++j) acc[i][j] = (f32x4){0.f, 0.f, 0.f, 0.f};

  int srow = tid >> 3, grp = tid & 7, scol = grp * 8;
  bf16x8 ar[4];
  f32x4 br0[4], br1[4];
#pragma unroll
  for (int k = 0; k < 4; ++k) {
    int rr = srow + k * 32;
    ar[k]  = *(const bf16x8*)(Abase + (size_t)rr * 512 + scol);
    br0[k] = *(const f32x4*)(Bbase + (size_t)rr * 512 + scol);
    br1[k] = *(const f32x4*)(Bbase + (size_t)rr * 512 + scol + 4);
  }
  for (int k0 = 0; k0 < 512; k0 += 64) {
#pragma unroll
    for (int k = 0; k < 4; ++k) {
      int rr = srow + k * 32;
      int w = SW(rr, grp);
      *(bf16x8*)(As + w) = ar[k];
      bf16x8 wb;
#pragma unroll
      for (int j = 0; j < 4; ++j) { wb[j] = (bf16)br0[k][j]; wb[4 + j] = (bf16)br1[k][j]; }
      *(bf16x8*)(Bs + w) = wb;
    }
    __syncthreads();
    if (k0 < 448) {
#pragma unroll
      for (int k = 0; k < 4; ++k) {
        int rr = srow + k * 32;
        ar[k]  = *(const bf16x8*)(Abase + (size_t)rr * 512 + k0 + 64 + scol);
        br0[k] = *(const f32x4*)(Bbase + (size_t)rr * 512 + k0 + 64 + scol);
        br1[k] = *(const f32x4*)(Bbase + (size_t)rr * 512 + k0 + 64 + scol + 4);
      }
    }
#pragma unroll
    for (int c = 0; c < 2; ++c) {
      bf16x8 af[4], bw[4];
#pragma unroll
      for (int mt = 0; mt < 4; ++mt)
        af[mt] = *(const bf16x8*)(As + SW(wm * 64 + mt * 16 + l15, c * 4 + quad));
#pragma unroll
      for (int nt = 0; nt < 4; ++nt)
        bw[nt] = *(const bf16x8*)(Bs + SW(wn * 64 + nt * 16 + l15, c * 4 + quad));
#pragma unroll
      for (int mt = 0; mt < 4; ++mt)
#pragma unroll
        for (int nt = 0; nt < 4; ++nt)
          acc[mt][nt] = __builtin_amdgcn_mfma_f32_16x16x32_bf16(
              bw[nt], af[mt], acc[mt][nt], 0, 0, 0);
    }
    __syncthreads();
  }
#pragma unroll
  for (int mt = 0; mt < 4; ++mt) {
    int m_g = mtile * 128 + wm * 64 + mt * 16 + l15;
#pragma unroll
    for (int nt = 0; nt < 4; ++nt) {
      int n_g = nb * 128 + wn * 64 + nt * 16 + quad * 4;
      f32x4 a = acc[mt][nt];
      f32x4 xr = *(const f32x4*)(x + (size_t)m_g * 512 + n_g);
      f32x4 bb = *(const f32x4*)(bo + n_g);
      f32x4 o;
#pragma unroll
      for (int r = 0; r < 4; ++r)
        o[r] = a[r] + bb[r] + xr[r];
      *(f32x4*)(out + (size_t)m_g * 512 + n_g) = o;
    }
  }
}

extern "C" void kernel_launch(void* const* d_in, const int* in_sizes, int n_in,
                              void* d_out, int out_size, void* d_ws, size_t ws_size,
                              hipStream_t stream) {
  const float* x     = (const float*)d_in[0];
  const float* wq    = (const float*)d_in[1];
  const float* wk    = (const float*)d_in[2];
  const float* wv    = (const float*)d_in[3];
  const float* wo    = (const float*)d_in[4];
  const float* bo    = (const float*)d_in[5];
  const float* gamma = (const float*)d_in[6];
  const float* beta  = (const float*)d_in[7];
  float* out = (float*)d_out;
  char* ws = (char*)d_ws;
  const size_t SZ = (size_t)8192 * 512 * sizeof(bf16);  // 8 MB
  bf16* h   = (bf16*)(ws);          // aliased with Ao (h dead before attn)
  bf16* Ao  = (bf16*)(ws);
  bf16* Qg  = (bf16*)(ws + SZ);
  bf16* Kg  = (bf16*)(ws + 2 * SZ);
  bf16* Vtg = (bf16*)(ws + 3 * SZ);

  ln_kernel<<<2048, 256, 0, stream>>>(x, gamma, beta, h);
  qkv_kernel<<<dim3(64, 12), 256, 0, stream>>>(h, wq, wk, wv, Qg, Kg, Vtg);
  attn_kernel<<<dim3(64, 16), 64, 0, stream>>>(Qg, Kg, Vtg, Ao);
  proj_kernel<<<dim3(64, 4), 256, 0, stream>>>(Ao, wo, bo, x, out);
}